// Round 9
// baseline (98.923 us; speedup 1.0000x reference)
//
#include <hip/hip_runtime.h>

// ChamferLoss: x,y (16,4096,3) f32 -> scalar.
// R9: R8 structure unchanged (db sliced inside wave, td=lane&7 8-way,
// RQ=8 queries/lane, full db in 64KB LDS, one scalar atomicAdd crosses
// blocks). Single change: inner math packed into float2 targeting
// v_pk_fma_f32 (VOP3P, gfx90a+): queries paired, db point splat. Inner
// body drops 56 -> 32 wave-instrs per 2-point iteration (24 pk_fma +
// 8 v_min3). R8 measured exactly 2x the 23.9us instr-issue floor with
// VALUBusy ~100% -> instruction-count-bound; packed math is the only
// lever that reduces instructions without touching numerics (packed FMA
// is bit-identical IEEE fp32).

#define NP 4096
#define NB 16
#define BLK 256
#define NZZ (2 * NB)            // 32 (dir,b)
#define RQ 8                    // queries per lane (4 float2 pairs)
#define RP (RQ / 2)             // query pairs per lane
#define QPB 256                 // queries per block (4 waves * 8 tq * RQ)
#define BPZ (NP / QPB)          // 16 blocks per zz
#define NBLOCKS (NZZ * BPZ)     // 512

typedef float f2 __attribute__((ext_vector_type(2)));

__global__ void chamfer_init(float* __restrict__ out) { out[0] = 0.0f; }

__global__ __launch_bounds__(BLK, 2) void chamfer_main(
    const float* __restrict__ x, const float* __restrict__ y,
    float* __restrict__ out) {
  const int bid  = blockIdx.x;
  const int zz   = bid >> 4;          // /BPZ
  const int qblk = bid & (BPZ - 1);
  const int dir  = zz >> 4;
  const int b    = zz & 15;

  const float* q_base = (dir == 0 ? x : y) + (size_t)b * NP * 3;
  const float* d_base = (dir == 0 ? y : x) + (size_t)b * NP * 3;

  // ---- stage full db (4096 pts) into LDS as (x,y,z,d2) ----
  __shared__ float4 dpt[NP];          // 64 KB
  for (int p = threadIdx.x; p < NP; p += BLK) {
    const float dx = d_base[p * 3 + 0];
    const float dy = d_base[p * 3 + 1];
    const float dz = d_base[p * 3 + 2];
    dpt[p] = make_float4(dx, dy, dz, dx * dx + dy * dy + dz * dz);
  }
  __syncthreads();

  const int wid  = threadIdx.x >> 6;  // wave 0..3
  const int lane = threadIdx.x & 63;
  const int td   = lane & 7;          // db slice 0..7
  const int tq   = lane >> 3;         // query group 0..7

  // this lane's RQ queries, packed as RP float2 pairs
  f2 qpx[RP], qpy[RP], qpz[RP], q2[RP], m[RP];
#pragma unroll
  for (int rr = 0; rr < RP; ++rr) {
    const int qi0 = qblk * QPB + wid * 64 + tq * RQ + 2 * rr;
    const float ax = q_base[qi0 * 3 + 0], bx = q_base[(qi0 + 1) * 3 + 0];
    const float ay = q_base[qi0 * 3 + 1], by = q_base[(qi0 + 1) * 3 + 1];
    const float az = q_base[qi0 * 3 + 2], bz = q_base[(qi0 + 1) * 3 + 2];
    q2[rr]  = (f2){ax * ax + ay * ay + az * az, bx * bx + by * by + bz * bz};
    qpx[rr] = (f2){-2.0f * ax, -2.0f * bx};
    qpy[rr] = (f2){-2.0f * ay, -2.0f * by};
    qpz[rr] = (f2){-2.0f * az, -2.0f * bz};
    m[rr]   = (f2){3.4e38f, 3.4e38f};
  }

  // ---- min over this lane's db slice: points t*8+td, t in [0,512) ----
#pragma unroll 4
  for (int t = 0; t < NP / 8; t += 2) {
    const float4 d0 = dpt[t * 8 + td];
    const float4 d1 = dpt[(t + 1) * 8 + td];
    const f2 d0x = {d0.x, d0.x}, d0y = {d0.y, d0.y}, d0z = {d0.z, d0.z}, d0w = {d0.w, d0.w};
    const f2 d1x = {d1.x, d1.x}, d1y = {d1.y, d1.y}, d1z = {d1.z, d1.z}, d1w = {d1.w, d1.w};
#pragma unroll
    for (int rr = 0; rr < RP; ++rr) {
      const f2 v0 = __builtin_elementwise_fma(d0x, qpx[rr],
                    __builtin_elementwise_fma(d0y, qpy[rr],
                    __builtin_elementwise_fma(d0z, qpz[rr], d0w)));
      const f2 v1 = __builtin_elementwise_fma(d1x, qpx[rr],
                    __builtin_elementwise_fma(d1y, qpy[rr],
                    __builtin_elementwise_fma(d1z, qpz[rr], d1w)));
      // per-component min3 (halves of a pk pair are plain VGPRs)
      m[rr].x = fminf(fminf(v0.x, v1.x), m[rr].x);
      m[rr].y = fminf(fminf(v0.y, v1.y), m[rr].y);
    }
  }

  // ---- reduce mins across the 8 td lanes of each octet ----
#pragma unroll
  for (int rr = 0; rr < RP; ++rr) {
    m[rr].x = fminf(m[rr].x, __shfl_xor(m[rr].x, 1));
    m[rr].y = fminf(m[rr].y, __shfl_xor(m[rr].y, 1));
    m[rr].x = fminf(m[rr].x, __shfl_xor(m[rr].x, 2));
    m[rr].y = fminf(m[rr].y, __shfl_xor(m[rr].y, 2));
    m[rr].x = fminf(m[rr].x, __shfl_xor(m[rr].x, 4));
    m[rr].y = fminf(m[rr].y, __shfl_xor(m[rr].y, 4));
  }

  // ---- epilogue: sqrt + partial mean (td==0 lanes only) ----
  float local = 0.0f;
  if (td == 0) {
#pragma unroll
    for (int rr = 0; rr < RP; ++rr) {
      local += sqrtf(fmaxf(q2[rr].x + m[rr].x, 0.0f) + 1e-6f);
      local += sqrtf(fmaxf(q2[rr].y + m[rr].y, 0.0f) + 1e-6f);
    }
    local *= (1.0f / (float)(NB * NP));
  }

  // wave reduce (octet leaders), then block reduce, one atomic per block
#pragma unroll
  for (int off = 32; off > 0; off >>= 1)
    local += __shfl_down(local, off);

  __shared__ float wsum[BLK / 64];
  if (lane == 0) wsum[wid] = local;
  __syncthreads();
  if (threadIdx.x == 0) {
    float s = 0.0f;
#pragma unroll
    for (int w = 0; w < BLK / 64; ++w) s += wsum[w];
    atomicAdd(out, s);
  }
}

extern "C" void kernel_launch(void* const* d_in, const int* in_sizes, int n_in,
                              void* d_out, int out_size, void* d_ws, size_t ws_size,
                              hipStream_t stream) {
  const float* x = (const float*)d_in[0];
  const float* y = (const float*)d_in[1];
  float* out = (float*)d_out;

  chamfer_init<<<1, 64, 0, stream>>>(out);
  chamfer_main<<<NBLOCKS, BLK, 0, stream>>>(x, y, out);
}